// Round 7
// baseline (159.039 us; speedup 1.0000x reference)
//
#include <hip/hip_runtime.h>
#include <hip/hip_bf16.h>

#define D 128
#define NBINS 157    // ceil(10000/64) bins of 64 nodes (dst >> 6)
#define BIN_CAP 5120 // mean 4076 + pad(<=448) + headroom
#define EPB 4096     // edges per scatter block (512 thr x 8)

// ---------- K1: fused [Y = X@W (unscaled)] + [bin_scatter] ----------
__global__ __launch_bounds__(512) void fused_gemm_scatter(
        const float* __restrict__ X, const float* __restrict__ W,
        float* __restrict__ Y,
        const int* __restrict__ src, const int* __restrict__ dst,
        int* __restrict__ binTotal, int* __restrict__ binned,
        int E, int N, int gGemm) {
    __shared__ float smem[D * D];   // 64 KB, dual-purpose
    int tid = threadIdx.x;

    if ((int)blockIdx.x < gGemm) {
        // ---- GEMM path: 32 rows/block, 8 waves x 4 rows ----
        {
            const float4* W4 = (const float4*)W;
            float4* Ws4 = (float4*)smem;
            #pragma unroll
            for (int i = 0; i < 8; ++i)
                Ws4[tid + 512 * i] = W4[tid + 512 * i];
        }
        __syncthreads();
        const float2* Ws2 = (const float2*)smem;
        int col2 = tid & 63;
        int wv   = __builtin_amdgcn_readfirstlane(tid >> 6);   // 0..7
        int row0 = blockIdx.x * 32 + wv * 4;
        if (row0 >= N) return;

        const float4* xr[4];
        #pragma unroll
        for (int r = 0; r < 4; ++r) {
            int rr = row0 + r; if (rr > N - 1) rr = N - 1;
            xr[r] = (const float4*)(X + (size_t)rr * D);
        }
        float accx[4] = {0.f, 0.f, 0.f, 0.f};
        float accy[4] = {0.f, 0.f, 0.f, 0.f};
        #pragma unroll 8
        for (int kb = 0; kb < 32; ++kb) {
            float4 xv[4];
            #pragma unroll
            for (int r = 0; r < 4; ++r) xv[r] = xr[r][kb];
            #pragma unroll
            for (int kk = 0; kk < 4; ++kk) {
                float2 w = Ws2[(4 * kb + kk) * 64 + col2];
                #pragma unroll
                for (int r = 0; r < 4; ++r) {
                    float xs = ((const float*)&xv[r])[kk];
                    accx[r] = fmaf(xs, w.x, accx[r]);
                    accy[r] = fmaf(xs, w.y, accy[r]);
                }
            }
        }
        #pragma unroll
        for (int r = 0; r < 4; ++r) {
            int rr = row0 + r;
            if (rr < N)
                ((float2*)Y)[(size_t)rr * 64 + col2] = make_float2(accx[r], accy[r]);
        }
    } else {
        // ---- scatter path ----
        int* cnt   = (int*)smem;
        int* loff  = cnt + 160;
        int* gbase = cnt + 320;
        int* scur  = cnt + 480;
        int* stage = cnt + 640;      // 4096 ints
        for (int b = tid; b < NBINS; b += 512) cnt[b] = 0;
        __syncthreads();

        int bid = blockIdx.x - gGemm;
        int base = bid * EPB + tid * 8;
        int s[8], dl[8], bn[8];
        int ne = 0;
        if (base + 8 <= E) {
            const int4* s4 = (const int4*)(src + base);
            const int4* d4 = (const int4*)(dst + base);
            int4 a0 = s4[0], a1 = s4[1], c0 = d4[0], c1 = d4[1];
            int ss[8] = {a0.x, a0.y, a0.z, a0.w, a1.x, a1.y, a1.z, a1.w};
            int dd[8] = {c0.x, c0.y, c0.z, c0.w, c1.x, c1.y, c1.z, c1.w};
            ne = 8;
            #pragma unroll
            for (int i = 0; i < 8; ++i) { s[i] = ss[i]; bn[i] = dd[i] >> 6; dl[i] = dd[i] & 63; }
        } else {
            for (int i = 0; i < 8; ++i) {
                int e = base + i;
                if (e < E) { s[ne] = src[e]; int d = dst[e]; bn[ne] = d >> 6; dl[ne] = d & 63; ++ne; }
            }
        }
        for (int i = 0; i < ne; ++i) atomicAdd(&cnt[bn[i]], 1);   // native ds_add (int)
        __syncthreads();

        if (tid < NBINS) gbase[tid] = atomicAdd(&binTotal[tid], cnt[tid]);
        if (tid < 64) {
            int c0 = (3 * tid     < NBINS) ? cnt[3 * tid    ] : 0;
            int c1 = (3 * tid + 1 < NBINS) ? cnt[3 * tid + 1] : 0;
            int c2 = (3 * tid + 2 < NBINS) ? cnt[3 * tid + 2] : 0;
            int tsum = c0 + c1 + c2;
            int incl = tsum;
            #pragma unroll
            for (int off = 1; off < 64; off <<= 1) {
                int t = __shfl_up(incl, off);
                if (tid >= off) incl += t;
            }
            int excl = incl - tsum;
            if (3 * tid     < NBINS) loff[3 * tid    ] = excl;
            if (3 * tid + 1 < NBINS) loff[3 * tid + 1] = excl + c0;
            if (3 * tid + 2 < NBINS) loff[3 * tid + 2] = excl + c0 + c1;
        }
        __syncthreads();
        if (tid < NBINS) scur[tid] = loff[tid];
        __syncthreads();

        for (int i = 0; i < ne; ++i) {
            int p = atomicAdd(&scur[bn[i]], 1);
            stage[p] = s[i] | (dl[i] << 14);      // src | dstLocal<<14
        }
        __syncthreads();

        int wv = tid >> 6, lane = tid & 63;
        for (int b = wv; b < NBINS; b += 8) {
            int n = cnt[b], so = loff[b], go = b * BIN_CAP + gbase[b];
            for (int i = lane; i < n; i += 64) binned[go + i] = stage[so + i];
        }
    }
}

// ---------- K2: counting sort (padded to x8 w/ sentinel N) + dinv + scale Y ----------
__global__ __launch_bounds__(256) void sort_bins(const int* __restrict__ binTotal,
                                                 const int* __restrict__ binned,
                                                 unsigned short* __restrict__ csr16,
                                                 float* __restrict__ dinv,
                                                 int* __restrict__ nodeStart,
                                                 int* __restrict__ nodeEnd,
                                                 float* __restrict__ Y, int N) {
    __shared__ int h[4][64];
    __shared__ int cur[4][64];
    __shared__ float sdinv[64];
    __shared__ int padTot;
    __shared__ int stage[BIN_CAP];
    int b = blockIdx.x, tid = threadIdx.x;
    int wv = tid >> 6, lane = tid & 63;
    int cntb = binTotal[b];
    h[wv][lane] = 0;
    __syncthreads();
    const int* bp = binned + b * BIN_CAP;
    for (int i = tid; i < cntb; i += 256) atomicAdd(&h[wv][bp[i] >> 14], 1);
    __syncthreads();
    if (tid < 64) {
        int d0 = h[0][tid], d1 = h[1][tid], d2 = h[2][tid], d3 = h[3][tid];
        int deg = d0 + d1 + d2 + d3;
        int pdeg = (deg + 7) & ~7;            // pad to multiple of 8 (0 stays 0)
        int incl = pdeg;
        #pragma unroll
        for (int off = 1; off < 64; off <<= 1) {
            int t = __shfl_up(incl, off);
            if (tid >= off) incl += t;
        }
        int excl = incl - pdeg;
        cur[0][tid] = excl;
        cur[1][tid] = excl + d0;
        cur[2][tid] = excl + d0 + d1;
        cur[3][tid] = excl + d0 + d1 + d2;
        float dv = rsqrtf((float)(deg + 1));  // +1 self loop (true degree)
        sdinv[tid] = dv;
        if (tid == 63) padTot = incl;         // total padded count
        int node = b * 64 + tid;
        if (node < N) {
            dinv[node]      = dv;
            nodeStart[node] = b * BIN_CAP + excl;
            nodeEnd[node]   = b * BIN_CAP + excl + pdeg;   // padded end
        }
    }
    __syncthreads();
    int cntPad = padTot;
    // init stage with sentinel (row N = zero row), then scatter real edges
    for (int i = tid; i < cntPad; i += 256) stage[i] = N;
    __syncthreads();
    for (int i = tid; i < cntb; i += 256) {
        int p = bp[i];
        int pos = atomicAdd(&cur[wv][p >> 14], 1);
        stage[pos] = p & 0x3FFF;
    }
    // in-place scale: Z rows of this bin *= dinv (rows owned exclusively)
    {
        float4* Y4 = (float4*)Y;
        #pragma unroll
        for (int i = 0; i < 8; ++i) {
            int idx = tid + 256 * i;            // 64 rows x 32 float4
            int row = idx >> 5, c = idx & 31;
            int node = b * 64 + row;
            if (node < N) {
                float4 v = Y4[(size_t)node * 32 + c];
                float dv = sdinv[row];
                v.x *= dv; v.y *= dv; v.z *= dv; v.w *= dv;
                Y4[(size_t)node * 32 + c] = v;
            }
        }
    }
    // zero the sentinel row N once (persists: gemm2 writes only rows < N)
    if (b == 0) {
        float4* Y4 = (float4*)Y;
        if (tid < 32) Y4[(size_t)N * 32 + tid] = make_float4(0.f, 0.f, 0.f, 0.f);
    }
    __syncthreads();
    unsigned short* bw = csr16 + b * BIN_CAP;
    for (int i = tid; i < cntPad; i += 256) bw[i] = (unsigned short)stage[i];
}

// ---------- GEMM (layer 2): Z[row] = (X[row] @ W) * dinv[row] ----------
__global__ __launch_bounds__(256) void gemm_scale(const float* __restrict__ X,
                                                  const float* __restrict__ W,
                                                  const float* __restrict__ dinv,
                                                  float* __restrict__ Z, int N) {
    __shared__ float Ws[D * D];
    {
        const float4* W4 = (const float4*)W;
        float4* Ws4 = (float4*)Ws;
        #pragma unroll
        for (int i = 0; i < 16; ++i)
            Ws4[threadIdx.x + 256 * i] = W4[threadIdx.x + 256 * i];
    }
    __syncthreads();
    const float2* Ws2 = (const float2*)Ws;
    int col2 = threadIdx.x & 63;
    int wv   = __builtin_amdgcn_readfirstlane(threadIdx.x >> 6);
    int row0 = blockIdx.x * 16 + wv * 4;
    if (row0 >= N) return;

    const float4* xr[4];
    #pragma unroll
    for (int r = 0; r < 4; ++r) {
        int rr = row0 + r; if (rr > N - 1) rr = N - 1;
        xr[r] = (const float4*)(X + (size_t)rr * D);
    }
    float accx[4] = {0.f, 0.f, 0.f, 0.f};
    float accy[4] = {0.f, 0.f, 0.f, 0.f};
    #pragma unroll 8
    for (int kb = 0; kb < 32; ++kb) {
        float4 xv[4];
        #pragma unroll
        for (int r = 0; r < 4; ++r) xv[r] = xr[r][kb];
        #pragma unroll
        for (int kk = 0; kk < 4; ++kk) {
            float2 w = Ws2[(4 * kb + kk) * 64 + col2];
            #pragma unroll
            for (int r = 0; r < 4; ++r) {
                float xs = ((const float*)&xv[r])[kk];
                accx[r] = fmaf(xs, w.x, accx[r]);
                accy[r] = fmaf(xs, w.y, accy[r]);
            }
        }
    }
    #pragma unroll
    for (int r = 0; r < 4; ++r) {
        int rr = row0 + r;
        if (rr < N) {
            float dv = dinv[rr];
            ((float2*)Z)[(size_t)rr * 64 + col2] = make_float2(accx[r] * dv, accy[r] * dv);
        }
    }
}

// ---------- aggregation: XCD-sliced, float4 gathers, branch-free (padded CSR) ----------
__global__ __launch_bounds__(256) void aggregate(const float* __restrict__ Z,
                                                 const int* __restrict__ nodeStart,
                                                 const int* __restrict__ nodeEnd,
                                                 const unsigned short* __restrict__ csr16,
                                                 const float* __restrict__ dinv,
                                                 const float* __restrict__ bias,
                                                 float* __restrict__ Out, int N) {
    int s    = blockIdx.x & 3;
    int wv   = __builtin_amdgcn_readfirstlane(threadIdx.x >> 6);
    int node = (blockIdx.x >> 2) * 4 + wv;
    if (node >= N) return;
    int lane = threadIdx.x & 63;
    int grp  = lane >> 3;
    int l8   = lane & 7;
    int off4 = s * 8 + l8;

    const float4* Z4 = (const float4*)Z;
    float ax = 0.f, ay = 0.f, az = 0.f, aw = 0.f;
    int e   = nodeStart[node];
    int end = nodeEnd[node];                // padded: (end - e) % 8 == 0
    while (e < end) {
        int cnt = end - e; if (cnt > 64) cnt = 64;
        int my = (lane < cnt) ? (int)csr16[e + lane] : 0;
        int rounds = cnt >> 3;
        #pragma unroll 8
        for (int j = 0; j < rounds; ++j) {
            int idx = __shfl(my, j * 8 + grp);
            float4 v = Z4[idx * 32 + off4];
            ax += v.x; ay += v.y; az += v.z; aw += v.w;
        }
        e += cnt;
    }
    #pragma unroll
    for (int m = 8; m <= 32; m <<= 1) {
        ax += __shfl_xor(ax, m);
        ay += __shfl_xor(ay, m);
        az += __shfl_xor(az, m);
        aw += __shfl_xor(aw, m);
    }
    if (lane < 8) {
        float4 self = Z4[node * 32 + off4];
        float dv = dinv[node];
        float4 b4 = ((const float4*)bias)[off4];
        float4 o;
        o.x = (ax + self.x) * dv + b4.x;
        o.y = (ay + self.y) * dv + b4.y;
        o.z = (az + self.z) * dv + b4.z;
        o.w = (aw + self.w) * dv + b4.w;
        ((float4*)Out)[node * 32 + off4] = o;
    }
}

extern "C" void kernel_launch(void* const* d_in, const int* in_sizes, int n_in,
                              void* d_out, int out_size, void* d_ws, size_t ws_size,
                              hipStream_t stream) {
    const float* X  = (const float*)d_in[0];
    const int*   ed = (const int*)d_in[1];
    const float* W1 = (const float*)d_in[2];
    const float* b1 = (const float*)d_in[3];
    const float* W2 = (const float*)d_in[4];
    const float* b2 = (const float*)d_in[5];
    float* out = (float*)d_out;

    const int N = in_sizes[0] / D;       // 10000
    const int E = in_sizes[1] / 2;       // 640000
    const int* src = ed;
    const int* dst = ed + E;

    char* w = (char*)d_ws;
    float* Z          = (float*)w;            w += (size_t)(N + 1) * D * sizeof(float); // +1 sentinel row
    int*   binned     = (int*)w;              w += (size_t)NBINS * BIN_CAP * sizeof(int);
    unsigned short* csr16 = (unsigned short*)w; w += (size_t)NBINS * BIN_CAP * sizeof(unsigned short);
    float* dinv       = (float*)w;            w += (size_t)N * sizeof(float);
    int*   nodeStart  = (int*)w;              w += (size_t)N * sizeof(int);
    int*   nodeEnd    = (int*)w;              w += (size_t)N * sizeof(int);
    int*   binTotal   = (int*)w;              w += (size_t)NBINS * sizeof(int);

    hipMemsetAsync(binTotal, 0, NBINS * sizeof(int), stream);

    int gGemm1 = (N + 31) / 32;                 // 313
    int gScat  = (E + EPB - 1) / EPB;           // 157
    fused_gemm_scatter<<<gGemm1 + gScat, 512, 0, stream>>>(
        X, W1, Z, src, dst, binTotal, binned, E, N, gGemm1);
    sort_bins<<<NBINS, 256, 0, stream>>>(binTotal, binned, csr16, dinv,
                                         nodeStart, nodeEnd, Z, N);

    int gAgg = ((N + 3) / 4) * 4;
    aggregate<<<gAgg, 256, 0, stream>>>(Z, nodeStart, nodeEnd, csr16, dinv, b1, out, N);

    int gGemm2 = (N + 15) / 16;
    gemm_scale<<<gGemm2, 256, 0, stream>>>(out, W2, dinv, Z, N);
    aggregate<<<gAgg, 256, 0, stream>>>(Z, nodeStart, nodeEnd, csr16, dinv, b2, out, N);
}

// Round 8
// 154.502 us; speedup vs baseline: 1.0294x; 1.0294x over previous
//
#include <hip/hip_runtime.h>
#include <hip/hip_bf16.h>

#define D 128
#define NBINS 157    // ceil(10000/64) bins of 64 nodes (dst >> 6)
#define BIN_CAP 5120 // mean 4076 + pad(<=448) + headroom
#define EPB 4096     // edges per scatter block (512 thr x 8)

__device__ __forceinline__ unsigned rne_bf16(float f) {
    unsigned u = __float_as_uint(f);
    return (u + 0x7FFFu + ((u >> 16) & 1u)) >> 16;
}
__device__ __forceinline__ float bf16_lo(unsigned u) { return __uint_as_float(u << 16); }
__device__ __forceinline__ float bf16_hi(unsigned u) { return __uint_as_float(u & 0xFFFF0000u); }

// ---------- K1: fused [Y = X@W (unscaled, fp32)] + [bin_scatter] ----------
__global__ __launch_bounds__(512) void fused_gemm_scatter(
        const float* __restrict__ X, const float* __restrict__ W,
        float* __restrict__ Y,
        const int* __restrict__ src, const int* __restrict__ dst,
        int* __restrict__ binTotal, int* __restrict__ binned,
        int E, int N, int gGemm) {
    __shared__ float smem[D * D];   // 64 KB, dual-purpose
    int tid = threadIdx.x;

    if ((int)blockIdx.x < gGemm) {
        {
            const float4* W4 = (const float4*)W;
            float4* Ws4 = (float4*)smem;
            #pragma unroll
            for (int i = 0; i < 8; ++i)
                Ws4[tid + 512 * i] = W4[tid + 512 * i];
        }
        __syncthreads();
        const float2* Ws2 = (const float2*)smem;
        int col2 = tid & 63;
        int wv   = __builtin_amdgcn_readfirstlane(tid >> 6);   // 0..7
        int row0 = blockIdx.x * 32 + wv * 4;
        if (row0 >= N) return;

        const float4* xr[4];
        #pragma unroll
        for (int r = 0; r < 4; ++r) {
            int rr = row0 + r; if (rr > N - 1) rr = N - 1;
            xr[r] = (const float4*)(X + (size_t)rr * D);
        }
        float accx[4] = {0.f, 0.f, 0.f, 0.f};
        float accy[4] = {0.f, 0.f, 0.f, 0.f};
        #pragma unroll 8
        for (int kb = 0; kb < 32; ++kb) {
            float4 xv[4];
            #pragma unroll
            for (int r = 0; r < 4; ++r) xv[r] = xr[r][kb];
            #pragma unroll
            for (int kk = 0; kk < 4; ++kk) {
                float2 w = Ws2[(4 * kb + kk) * 64 + col2];
                #pragma unroll
                for (int r = 0; r < 4; ++r) {
                    float xs = ((const float*)&xv[r])[kk];
                    accx[r] = fmaf(xs, w.x, accx[r]);
                    accy[r] = fmaf(xs, w.y, accy[r]);
                }
            }
        }
        #pragma unroll
        for (int r = 0; r < 4; ++r) {
            int rr = row0 + r;
            if (rr < N)
                ((float2*)Y)[(size_t)rr * 64 + col2] = make_float2(accx[r], accy[r]);
        }
    } else {
        int* cnt   = (int*)smem;
        int* loff  = cnt + 160;
        int* gbase = cnt + 320;
        int* scur  = cnt + 480;
        int* stage = cnt + 640;      // 4096 ints
        for (int b = tid; b < NBINS; b += 512) cnt[b] = 0;
        __syncthreads();

        int bid = blockIdx.x - gGemm;
        int base = bid * EPB + tid * 8;
        int s[8], dl[8], bn[8];
        int ne = 0;
        if (base + 8 <= E) {
            const int4* s4 = (const int4*)(src + base);
            const int4* d4 = (const int4*)(dst + base);
            int4 a0 = s4[0], a1 = s4[1], c0 = d4[0], c1 = d4[1];
            int ss[8] = {a0.x, a0.y, a0.z, a0.w, a1.x, a1.y, a1.z, a1.w};
            int dd[8] = {c0.x, c0.y, c0.z, c0.w, c1.x, c1.y, c1.z, c1.w};
            ne = 8;
            #pragma unroll
            for (int i = 0; i < 8; ++i) { s[i] = ss[i]; bn[i] = dd[i] >> 6; dl[i] = dd[i] & 63; }
        } else {
            for (int i = 0; i < 8; ++i) {
                int e = base + i;
                if (e < E) { s[ne] = src[e]; int d = dst[e]; bn[ne] = d >> 6; dl[ne] = d & 63; ++ne; }
            }
        }
        for (int i = 0; i < ne; ++i) atomicAdd(&cnt[bn[i]], 1);   // native ds_add (int)
        __syncthreads();

        if (tid < NBINS) gbase[tid] = atomicAdd(&binTotal[tid], cnt[tid]);
        if (tid < 64) {
            int c0 = (3 * tid     < NBINS) ? cnt[3 * tid    ] : 0;
            int c1 = (3 * tid + 1 < NBINS) ? cnt[3 * tid + 1] : 0;
            int c2 = (3 * tid + 2 < NBINS) ? cnt[3 * tid + 2] : 0;
            int tsum = c0 + c1 + c2;
            int incl = tsum;
            #pragma unroll
            for (int off = 1; off < 64; off <<= 1) {
                int t = __shfl_up(incl, off);
                if (tid >= off) incl += t;
            }
            int excl = incl - tsum;
            if (3 * tid     < NBINS) loff[3 * tid    ] = excl;
            if (3 * tid + 1 < NBINS) loff[3 * tid + 1] = excl + c0;
            if (3 * tid + 2 < NBINS) loff[3 * tid + 2] = excl + c0 + c1;
        }
        __syncthreads();
        if (tid < NBINS) scur[tid] = loff[tid];
        __syncthreads();

        for (int i = 0; i < ne; ++i) {
            int p = atomicAdd(&scur[bn[i]], 1);
            stage[p] = s[i] | (dl[i] << 14);      // src | dstLocal<<14
        }
        __syncthreads();

        int wv = tid >> 6, lane = tid & 63;
        for (int b = wv; b < NBINS; b += 8) {
            int n = cnt[b], so = loff[b], go = b * BIN_CAP + gbase[b];
            for (int i = lane; i < n; i += 64) binned[go + i] = stage[so + i];
        }
    }
}

// ---------- K2: counting sort (padded x8, sentinel N) + dinv + scale Y -> bf16 Zb ----------
__global__ __launch_bounds__(256) void sort_bins(const int* __restrict__ binTotal,
                                                 const int* __restrict__ binned,
                                                 unsigned short* __restrict__ csr16,
                                                 float* __restrict__ dinv,
                                                 int* __restrict__ nodeStart,
                                                 int* __restrict__ nodeEnd,
                                                 const float* __restrict__ Y,
                                                 unsigned* __restrict__ Zb, int N) {
    __shared__ int h[4][64];
    __shared__ int cur[4][64];
    __shared__ float sdinv[64];
    __shared__ int padTot;
    __shared__ int stage[BIN_CAP];
    int b = blockIdx.x, tid = threadIdx.x;
    int wv = tid >> 6, lane = tid & 63;
    int cntb = binTotal[b];
    h[wv][lane] = 0;
    __syncthreads();
    const int* bp = binned + b * BIN_CAP;
    for (int i = tid; i < cntb; i += 256) atomicAdd(&h[wv][bp[i] >> 14], 1);
    __syncthreads();
    if (tid < 64) {
        int d0 = h[0][tid], d1 = h[1][tid], d2 = h[2][tid], d3 = h[3][tid];
        int deg = d0 + d1 + d2 + d3;
        int pdeg = (deg + 7) & ~7;            // pad to multiple of 8
        int incl = pdeg;
        #pragma unroll
        for (int off = 1; off < 64; off <<= 1) {
            int t = __shfl_up(incl, off);
            if (tid >= off) incl += t;
        }
        int excl = incl - pdeg;
        cur[0][tid] = excl;
        cur[1][tid] = excl + d0;
        cur[2][tid] = excl + d0 + d1;
        cur[3][tid] = excl + d0 + d1 + d2;
        float dv = rsqrtf((float)(deg + 1));  // +1 self loop
        sdinv[tid] = dv;
        if (tid == 63) padTot = incl;
        int node = b * 64 + tid;
        if (node < N) {
            dinv[node]      = dv;
            nodeStart[node] = b * BIN_CAP + excl;
            nodeEnd[node]   = b * BIN_CAP + excl + pdeg;
        }
    }
    __syncthreads();
    int cntPad = padTot;
    for (int i = tid; i < cntPad; i += 256) stage[i] = N;   // sentinel = zero row
    __syncthreads();
    for (int i = tid; i < cntb; i += 256) {
        int p = bp[i];
        int pos = atomicAdd(&cur[wv][p >> 14], 1);
        stage[pos] = p & 0x3FFF;
    }
    // scale + convert: Zb[node] = bf16(Y[node] * dinv)  (rows owned exclusively)
    {
        const float4* Y4 = (const float4*)Y;
        uint2* Zb2 = (uint2*)Zb;            // 8 B = 4 bf16
        #pragma unroll
        for (int i = 0; i < 8; ++i) {
            int idx = tid + 256 * i;        // 64 rows x 32 quads
            int row = idx >> 5, c = idx & 31;
            int node = b * 64 + row;
            if (node < N) {
                float4 v = Y4[(size_t)node * 32 + c];
                float dv = sdinv[row];
                uint2 o;
                o.x = (rne_bf16(v.y * dv) << 16) | rne_bf16(v.x * dv);
                o.y = (rne_bf16(v.w * dv) << 16) | rne_bf16(v.z * dv);
                Zb2[(size_t)node * 32 + c] = o;
            }
        }
    }
    // zero sentinel row N (persists for layer 2: gemm writes only rows < N)
    if (b == 0 && tid < 64) Zb[(size_t)N * 64 + tid] = 0u;
    __syncthreads();
    unsigned short* bw = csr16 + b * BIN_CAP;
    for (int i = tid; i < cntPad; i += 256) bw[i] = (unsigned short)stage[i];
}

// ---------- GEMM (layer 2): Zb[row] = bf16((X[row] @ W) * dinv[row]) ----------
__global__ __launch_bounds__(256) void gemm_scale(const float* __restrict__ X,
                                                  const float* __restrict__ W,
                                                  const float* __restrict__ dinv,
                                                  unsigned* __restrict__ Zb, int N) {
    __shared__ float Ws[D * D];
    {
        const float4* W4 = (const float4*)W;
        float4* Ws4 = (float4*)Ws;
        #pragma unroll
        for (int i = 0; i < 16; ++i)
            Ws4[threadIdx.x + 256 * i] = W4[threadIdx.x + 256 * i];
    }
    __syncthreads();
    const float2* Ws2 = (const float2*)Ws;
    int col2 = threadIdx.x & 63;
    int wv   = __builtin_amdgcn_readfirstlane(threadIdx.x >> 6);
    int row0 = blockIdx.x * 16 + wv * 4;
    if (row0 >= N) return;

    const float4* xr[4];
    #pragma unroll
    for (int r = 0; r < 4; ++r) {
        int rr = row0 + r; if (rr > N - 1) rr = N - 1;
        xr[r] = (const float4*)(X + (size_t)rr * D);
    }
    float accx[4] = {0.f, 0.f, 0.f, 0.f};
    float accy[4] = {0.f, 0.f, 0.f, 0.f};
    #pragma unroll 8
    for (int kb = 0; kb < 32; ++kb) {
        float4 xv[4];
        #pragma unroll
        for (int r = 0; r < 4; ++r) xv[r] = xr[r][kb];
        #pragma unroll
        for (int kk = 0; kk < 4; ++kk) {
            float2 w = Ws2[(4 * kb + kk) * 64 + col2];
            #pragma unroll
            for (int r = 0; r < 4; ++r) {
                float xs = ((const float*)&xv[r])[kk];
                accx[r] = fmaf(xs, w.x, accx[r]);
                accy[r] = fmaf(xs, w.y, accy[r]);
            }
        }
    }
    #pragma unroll
    for (int r = 0; r < 4; ++r) {
        int rr = row0 + r;
        if (rr < N) {
            float dv = dinv[rr];
            Zb[(size_t)rr * 64 + col2] =
                (rne_bf16(accy[r] * dv) << 16) | rne_bf16(accx[r] * dv);
        }
    }
}

// ---------- aggregation: XCD-sliced, bf16 uint2 gathers (8 B/lane, 64 B/edge-slice) ----------
__global__ __launch_bounds__(256) void aggregate(const unsigned* __restrict__ Zb,
                                                 const int* __restrict__ nodeStart,
                                                 const int* __restrict__ nodeEnd,
                                                 const unsigned short* __restrict__ csr16,
                                                 const float* __restrict__ dinv,
                                                 const float* __restrict__ bias,
                                                 float* __restrict__ Out, int N) {
    int s    = blockIdx.x & 3;
    int wv   = __builtin_amdgcn_readfirstlane(threadIdx.x >> 6);
    int node = (blockIdx.x >> 2) * 4 + wv;
    if (node >= N) return;
    int lane = threadIdx.x & 63;
    int grp  = lane >> 3;
    int l8   = lane & 7;
    int off  = s * 8 + l8;                  // uint2 slot within 32-slot row

    const uint2* Zb2 = (const uint2*)Zb;
    float ax = 0.f, ay = 0.f, az = 0.f, aw = 0.f;
    int e   = nodeStart[node];
    int end = nodeEnd[node];                // padded: (end - e) % 8 == 0
    while (e < end) {
        int cnt = end - e; if (cnt > 64) cnt = 64;
        int my = (lane < cnt) ? (int)csr16[e + lane] : 0;
        int rounds = cnt >> 3;
        #pragma unroll 8
        for (int j = 0; j < rounds; ++j) {
            int idx = __shfl(my, j * 8 + grp);
            uint2 u = Zb2[idx * 32 + off];
            ax += bf16_lo(u.x); ay += bf16_hi(u.x);
            az += bf16_lo(u.y); aw += bf16_hi(u.y);
        }
        e += cnt;
    }
    #pragma unroll
    for (int m = 8; m <= 32; m <<= 1) {
        ax += __shfl_xor(ax, m);
        ay += __shfl_xor(ay, m);
        az += __shfl_xor(az, m);
        aw += __shfl_xor(aw, m);
    }
    if (lane < 8) {
        uint2 su = Zb2[node * 32 + off];
        float dv = dinv[node];
        float4 b4 = ((const float4*)bias)[off];
        float4 o;
        o.x = (ax + bf16_lo(su.x)) * dv + b4.x;
        o.y = (ay + bf16_hi(su.x)) * dv + b4.y;
        o.z = (az + bf16_lo(su.y)) * dv + b4.z;
        o.w = (aw + bf16_hi(su.y)) * dv + b4.w;
        ((float4*)Out)[node * 32 + off] = o;
    }
}

extern "C" void kernel_launch(void* const* d_in, const int* in_sizes, int n_in,
                              void* d_out, int out_size, void* d_ws, size_t ws_size,
                              hipStream_t stream) {
    const float* X  = (const float*)d_in[0];
    const int*   ed = (const int*)d_in[1];
    const float* W1 = (const float*)d_in[2];
    const float* b1 = (const float*)d_in[3];
    const float* W2 = (const float*)d_in[4];
    const float* b2 = (const float*)d_in[5];
    float* out = (float*)d_out;

    const int N = in_sizes[0] / D;       // 10000
    const int E = in_sizes[1] / 2;       // 640000
    const int* src = ed;
    const int* dst = ed + E;

    char* w = (char*)d_ws;
    float*    Y        = (float*)w;            w += (size_t)N * D * sizeof(float);
    unsigned* Zb       = (unsigned*)w;         w += (size_t)(N + 1) * 64 * sizeof(unsigned);
    int*      binned   = (int*)w;              w += (size_t)NBINS * BIN_CAP * sizeof(int);
    unsigned short* csr16 = (unsigned short*)w; w += (size_t)NBINS * BIN_CAP * sizeof(unsigned short);
    float*    dinv     = (float*)w;            w += (size_t)N * sizeof(float);
    int*      nodeStart= (int*)w;              w += (size_t)N * sizeof(int);
    int*      nodeEnd  = (int*)w;              w += (size_t)N * sizeof(int);
    int*      binTotal = (int*)w;              w += (size_t)NBINS * sizeof(int);

    hipMemsetAsync(binTotal, 0, NBINS * sizeof(int), stream);

    int gGemm1 = (N + 31) / 32;                 // 313
    int gScat  = (E + EPB - 1) / EPB;           // 157
    fused_gemm_scatter<<<gGemm1 + gScat, 512, 0, stream>>>(
        X, W1, Y, src, dst, binTotal, binned, E, N, gGemm1);
    sort_bins<<<NBINS, 256, 0, stream>>>(binTotal, binned, csr16, dinv,
                                         nodeStart, nodeEnd, Y, Zb, N);

    int gAgg = ((N + 3) / 4) * 4;
    aggregate<<<gAgg, 256, 0, stream>>>(Zb, nodeStart, nodeEnd, csr16, dinv, b1, out, N);

    int gGemm2 = (N + 15) / 16;
    gemm_scale<<<gGemm2, 256, 0, stream>>>(out, W2, dinv, Zb, N);
    aggregate<<<gAgg, 256, 0, stream>>>(Zb, nodeStart, nodeEnd, csr16, dinv, b2, out, N);
}

// Round 9
// 143.057 us; speedup vs baseline: 1.1117x; 1.0800x over previous
//
#include <hip/hip_runtime.h>
#include <hip/hip_bf16.h>

#define D 128
#define NBINS 157    // ceil(10000/64) bins of 64 nodes (dst >> 6)
#define BIN_CAP 5120 // mean 4076 + pad(<=448) + headroom
#define EPB 4096     // edges per scatter block (512 thr x 8)

__device__ __forceinline__ unsigned rne_bf16(float f) {
    unsigned u = __float_as_uint(f);
    return (u + 0x7FFFu + ((u >> 16) & 1u)) >> 16;
}
__device__ __forceinline__ float bf16_lo(unsigned u) { return __uint_as_float(u << 16); }
__device__ __forceinline__ float bf16_hi(unsigned u) { return __uint_as_float(u & 0xFFFF0000u); }

// ---------- K1: fused [Y = X@W (unscaled, fp32)] + [bin_scatter] ----------
__global__ __launch_bounds__(512) void fused_gemm_scatter(
        const float* __restrict__ X, const float* __restrict__ W,
        float* __restrict__ Y,
        const int* __restrict__ src, const int* __restrict__ dst,
        int* __restrict__ binTotal, int* __restrict__ binned,
        int E, int N, int gGemm) {
    __shared__ float smem[D * D];   // 64 KB, dual-purpose
    int tid = threadIdx.x;

    if ((int)blockIdx.x < gGemm) {
        {
            const float4* W4 = (const float4*)W;
            float4* Ws4 = (float4*)smem;
            #pragma unroll
            for (int i = 0; i < 8; ++i)
                Ws4[tid + 512 * i] = W4[tid + 512 * i];
        }
        __syncthreads();
        const float2* Ws2 = (const float2*)smem;
        int col2 = tid & 63;
        int wv   = __builtin_amdgcn_readfirstlane(tid >> 6);   // 0..7
        int row0 = blockIdx.x * 32 + wv * 4;
        if (row0 >= N) return;

        const float4* xr[4];
        #pragma unroll
        for (int r = 0; r < 4; ++r) {
            int rr = row0 + r; if (rr > N - 1) rr = N - 1;
            xr[r] = (const float4*)(X + (size_t)rr * D);
        }
        float accx[4] = {0.f, 0.f, 0.f, 0.f};
        float accy[4] = {0.f, 0.f, 0.f, 0.f};
        #pragma unroll 8
        for (int kb = 0; kb < 32; ++kb) {
            float4 xv[4];
            #pragma unroll
            for (int r = 0; r < 4; ++r) xv[r] = xr[r][kb];
            #pragma unroll
            for (int kk = 0; kk < 4; ++kk) {
                float2 w = Ws2[(4 * kb + kk) * 64 + col2];
                #pragma unroll
                for (int r = 0; r < 4; ++r) {
                    float xs = ((const float*)&xv[r])[kk];
                    accx[r] = fmaf(xs, w.x, accx[r]);
                    accy[r] = fmaf(xs, w.y, accy[r]);
                }
            }
        }
        #pragma unroll
        for (int r = 0; r < 4; ++r) {
            int rr = row0 + r;
            if (rr < N)
                ((float2*)Y)[(size_t)rr * 64 + col2] = make_float2(accx[r], accy[r]);
        }
    } else {
        int* cnt   = (int*)smem;
        int* loff  = cnt + 160;
        int* gbase = cnt + 320;
        int* scur  = cnt + 480;
        int* stage = cnt + 640;      // 4096 ints
        for (int b = tid; b < NBINS; b += 512) cnt[b] = 0;
        __syncthreads();

        int bid = blockIdx.x - gGemm;
        int base = bid * EPB + tid * 8;
        int s[8], dl[8], bn[8];
        int ne = 0;
        if (base + 8 <= E) {
            const int4* s4 = (const int4*)(src + base);
            const int4* d4 = (const int4*)(dst + base);
            int4 a0 = s4[0], a1 = s4[1], c0 = d4[0], c1 = d4[1];
            int ss[8] = {a0.x, a0.y, a0.z, a0.w, a1.x, a1.y, a1.z, a1.w};
            int dd[8] = {c0.x, c0.y, c0.z, c0.w, c1.x, c1.y, c1.z, c1.w};
            ne = 8;
            #pragma unroll
            for (int i = 0; i < 8; ++i) { s[i] = ss[i]; bn[i] = dd[i] >> 6; dl[i] = dd[i] & 63; }
        } else {
            for (int i = 0; i < 8; ++i) {
                int e = base + i;
                if (e < E) { s[ne] = src[e]; int d = dst[e]; bn[ne] = d >> 6; dl[ne] = d & 63; ++ne; }
            }
        }
        for (int i = 0; i < ne; ++i) atomicAdd(&cnt[bn[i]], 1);   // native ds_add (int)
        __syncthreads();

        if (tid < NBINS) gbase[tid] = atomicAdd(&binTotal[tid], cnt[tid]);
        if (tid < 64) {
            int c0 = (3 * tid     < NBINS) ? cnt[3 * tid    ] : 0;
            int c1 = (3 * tid + 1 < NBINS) ? cnt[3 * tid + 1] : 0;
            int c2 = (3 * tid + 2 < NBINS) ? cnt[3 * tid + 2] : 0;
            int tsum = c0 + c1 + c2;
            int incl = tsum;
            #pragma unroll
            for (int off = 1; off < 64; off <<= 1) {
                int t = __shfl_up(incl, off);
                if (tid >= off) incl += t;
            }
            int excl = incl - tsum;
            if (3 * tid     < NBINS) loff[3 * tid    ] = excl;
            if (3 * tid + 1 < NBINS) loff[3 * tid + 1] = excl + c0;
            if (3 * tid + 2 < NBINS) loff[3 * tid + 2] = excl + c0 + c1;
        }
        __syncthreads();
        if (tid < NBINS) scur[tid] = loff[tid];
        __syncthreads();

        for (int i = 0; i < ne; ++i) {
            int p = atomicAdd(&scur[bn[i]], 1);
            stage[p] = s[i] | (dl[i] << 14);      // src | dstLocal<<14
        }
        __syncthreads();

        int wv = tid >> 6, lane = tid & 63;
        for (int b = wv; b < NBINS; b += 8) {
            int n = cnt[b], so = loff[b], go = b * BIN_CAP + gbase[b];
            for (int i = lane; i < n; i += 64) binned[go + i] = stage[so + i];
        }
    }
}

// ---------- K2: counting sort (padded x8, sentinel N) + dinv + scale Y -> bf16 Zb ----------
__global__ __launch_bounds__(256) void sort_bins(const int* __restrict__ binTotal,
                                                 const int* __restrict__ binned,
                                                 unsigned short* __restrict__ csr16,
                                                 float* __restrict__ dinv,
                                                 int* __restrict__ nodeStart,
                                                 int* __restrict__ nodeEnd,
                                                 const float* __restrict__ Y,
                                                 unsigned* __restrict__ Zb, int N) {
    __shared__ int h[4][64];
    __shared__ int cur[4][64];
    __shared__ float sdinv[64];
    __shared__ int padTot;
    __shared__ int stage[BIN_CAP];
    int b = blockIdx.x, tid = threadIdx.x;
    int wv = tid >> 6, lane = tid & 63;
    int cntb = binTotal[b];
    h[wv][lane] = 0;
    __syncthreads();
    const int* bp = binned + b * BIN_CAP;
    for (int i = tid; i < cntb; i += 256) atomicAdd(&h[wv][bp[i] >> 14], 1);
    __syncthreads();
    if (tid < 64) {
        int d0 = h[0][tid], d1 = h[1][tid], d2 = h[2][tid], d3 = h[3][tid];
        int deg = d0 + d1 + d2 + d3;
        int pdeg = (deg + 7) & ~7;            // pad to multiple of 8
        int incl = pdeg;
        #pragma unroll
        for (int off = 1; off < 64; off <<= 1) {
            int t = __shfl_up(incl, off);
            if (tid >= off) incl += t;
        }
        int excl = incl - pdeg;
        cur[0][tid] = excl;
        cur[1][tid] = excl + d0;
        cur[2][tid] = excl + d0 + d1;
        cur[3][tid] = excl + d0 + d1 + d2;
        float dv = rsqrtf((float)(deg + 1));  // +1 self loop
        sdinv[tid] = dv;
        if (tid == 63) padTot = incl;
        int node = b * 64 + tid;
        if (node < N) {
            dinv[node]      = dv;
            nodeStart[node] = b * BIN_CAP + excl;
            nodeEnd[node]   = b * BIN_CAP + excl + pdeg;
        }
    }
    __syncthreads();
    int cntPad = padTot;
    for (int i = tid; i < cntPad; i += 256) stage[i] = N;   // sentinel = zero row
    __syncthreads();
    for (int i = tid; i < cntb; i += 256) {
        int p = bp[i];
        int pos = atomicAdd(&cur[wv][p >> 14], 1);
        stage[pos] = p & 0x3FFF;
    }
    // scale + convert: Zb[node] = bf16(Y[node] * dinv)  (rows owned exclusively)
    {
        const float4* Y4 = (const float4*)Y;
        uint2* Zb2 = (uint2*)Zb;            // 8 B = 4 bf16
        #pragma unroll
        for (int i = 0; i < 8; ++i) {
            int idx = tid + 256 * i;        // 64 rows x 32 quads
            int row = idx >> 5, c = idx & 31;
            int node = b * 64 + row;
            if (node < N) {
                float4 v = Y4[(size_t)node * 32 + c];
                float dv = sdinv[row];
                uint2 o;
                o.x = (rne_bf16(v.y * dv) << 16) | rne_bf16(v.x * dv);
                o.y = (rne_bf16(v.w * dv) << 16) | rne_bf16(v.z * dv);
                Zb2[(size_t)node * 32 + c] = o;
            }
        }
    }
    // zero sentinel row N (persists for layer 2: gemm writes only rows < N)
    if (b == 0 && tid < 64) Zb[(size_t)N * 64 + tid] = 0u;
    __syncthreads();
    unsigned short* bw = csr16 + b * BIN_CAP;
    for (int i = tid; i < cntPad; i += 256) bw[i] = (unsigned short)stage[i];
}

// ---------- GEMM (layer 2): Zb[row] = bf16((X[row] @ W) * dinv[row]) ----------
__global__ __launch_bounds__(256) void gemm_scale(const float* __restrict__ X,
                                                  const float* __restrict__ W,
                                                  const float* __restrict__ dinv,
                                                  unsigned* __restrict__ Zb, int N) {
    __shared__ float Ws[D * D];
    {
        const float4* W4 = (const float4*)W;
        float4* Ws4 = (float4*)Ws;
        #pragma unroll
        for (int i = 0; i < 16; ++i)
            Ws4[threadIdx.x + 256 * i] = W4[threadIdx.x + 256 * i];
    }
    __syncthreads();
    const float2* Ws2 = (const float2*)Ws;
    int col2 = threadIdx.x & 63;
    int wv   = __builtin_amdgcn_readfirstlane(threadIdx.x >> 6);
    int row0 = blockIdx.x * 16 + wv * 4;
    if (row0 >= N) return;

    const float4* xr[4];
    #pragma unroll
    for (int r = 0; r < 4; ++r) {
        int rr = row0 + r; if (rr > N - 1) rr = N - 1;
        xr[r] = (const float4*)(X + (size_t)rr * D);
    }
    float accx[4] = {0.f, 0.f, 0.f, 0.f};
    float accy[4] = {0.f, 0.f, 0.f, 0.f};
    #pragma unroll 8
    for (int kb = 0; kb < 32; ++kb) {
        float4 xv[4];
        #pragma unroll
        for (int r = 0; r < 4; ++r) xv[r] = xr[r][kb];
        #pragma unroll
        for (int kk = 0; kk < 4; ++kk) {
            float2 w = Ws2[(4 * kb + kk) * 64 + col2];
            #pragma unroll
            for (int r = 0; r < 4; ++r) {
                float xs = ((const float*)&xv[r])[kk];
                accx[r] = fmaf(xs, w.x, accx[r]);
                accy[r] = fmaf(xs, w.y, accy[r]);
            }
        }
    }
    #pragma unroll
    for (int r = 0; r < 4; ++r) {
        int rr = row0 + r;
        if (rr < N) {
            float dv = dinv[rr];
            Zb[(size_t)rr * 64 + col2] =
                (rne_bf16(accy[r] * dv) << 16) | rne_bf16(accx[r] * dv);
        }
    }
}

// ---------- aggregation: full-row uint4 gathers, one wave per node ----------
// 4 edge-groups x 16 lanes; each lane gathers 16 B so a group covers the full
// 256 B bf16 row in ONE instruction (4 edges in flight per round).
__global__ __launch_bounds__(256) void aggregate(const unsigned* __restrict__ Zb,
                                                 const int* __restrict__ nodeStart,
                                                 const int* __restrict__ nodeEnd,
                                                 const unsigned short* __restrict__ csr16,
                                                 const float* __restrict__ dinv,
                                                 const float* __restrict__ bias,
                                                 float* __restrict__ Out, int N) {
    int wv   = __builtin_amdgcn_readfirstlane(threadIdx.x >> 6);
    int node = blockIdx.x * 4 + wv;
    if (node >= N) return;
    int lane = threadIdx.x & 63;
    int g    = lane >> 4;       // 0..3 edge sub-group
    int l16  = lane & 15;       // uint4 slot within 256 B row

    const uint4* Z4 = (const uint4*)Zb;     // row = 16 uint4
    float a0 = 0.f, a1 = 0.f, a2 = 0.f, a3 = 0.f;
    float a4 = 0.f, a5 = 0.f, a6 = 0.f, a7 = 0.f;
    int e   = nodeStart[node];
    int end = nodeEnd[node];                // padded: (end - e) % 8 == 0
    while (e < end) {
        int cnt = end - e; if (cnt > 64) cnt = 64;
        int my = (lane < cnt) ? (int)csr16[e + lane] : 0;
        int rounds = cnt >> 2;              // cnt % 8 == 0 => % 4 == 0
        #pragma unroll 16
        for (int j = 0; j < rounds; ++j) {
            int idx = __shfl(my, j * 4 + g);
            uint4 u = Z4[idx * 16 + l16];
            a0 += bf16_lo(u.x); a1 += bf16_hi(u.x);
            a2 += bf16_lo(u.y); a3 += bf16_hi(u.y);
            a4 += bf16_lo(u.z); a5 += bf16_hi(u.z);
            a6 += bf16_lo(u.w); a7 += bf16_hi(u.w);
        }
        e += cnt;
    }
    // reduce across the 4 edge-groups (lane bits 4..5)
    #pragma unroll
    for (int m = 16; m <= 32; m <<= 1) {
        a0 += __shfl_xor(a0, m); a1 += __shfl_xor(a1, m);
        a2 += __shfl_xor(a2, m); a3 += __shfl_xor(a3, m);
        a4 += __shfl_xor(a4, m); a5 += __shfl_xor(a5, m);
        a6 += __shfl_xor(a6, m); a7 += __shfl_xor(a7, m);
    }
    if (lane < 16) {
        uint4 su = Z4[node * 16 + l16];
        float dv = dinv[node];
        const float4* b4 = (const float4*)bias;
        float4 ba = b4[l16 * 2], bb = b4[l16 * 2 + 1];
        float4 o0, o1;
        o0.x = (a0 + bf16_lo(su.x)) * dv + ba.x;
        o0.y = (a1 + bf16_hi(su.x)) * dv + ba.y;
        o0.z = (a2 + bf16_lo(su.y)) * dv + ba.z;
        o0.w = (a3 + bf16_hi(su.y)) * dv + ba.w;
        o1.x = (a4 + bf16_lo(su.z)) * dv + bb.x;
        o1.y = (a5 + bf16_hi(su.z)) * dv + bb.y;
        o1.z = (a6 + bf16_lo(su.w)) * dv + bb.z;
        o1.w = (a7 + bf16_hi(su.w)) * dv + bb.w;
        float4* op = (float4*)Out + (size_t)node * 32 + l16 * 2;
        op[0] = o0;
        op[1] = o1;
    }
}

extern "C" void kernel_launch(void* const* d_in, const int* in_sizes, int n_in,
                              void* d_out, int out_size, void* d_ws, size_t ws_size,
                              hipStream_t stream) {
    const float* X  = (const float*)d_in[0];
    const int*   ed = (const int*)d_in[1];
    const float* W1 = (const float*)d_in[2];
    const float* b1 = (const float*)d_in[3];
    const float* W2 = (const float*)d_in[4];
    const float* b2 = (const float*)d_in[5];
    float* out = (float*)d_out;

    const int N = in_sizes[0] / D;       // 10000
    const int E = in_sizes[1] / 2;       // 640000
    const int* src = ed;
    const int* dst = ed + E;

    char* w = (char*)d_ws;
    float*    Y        = (float*)w;            w += (size_t)N * D * sizeof(float);
    unsigned* Zb       = (unsigned*)w;         w += (size_t)(N + 1) * 64 * sizeof(unsigned);
    int*      binned   = (int*)w;              w += (size_t)NBINS * BIN_CAP * sizeof(int);
    unsigned short* csr16 = (unsigned short*)w; w += (size_t)NBINS * BIN_CAP * sizeof(unsigned short);
    float*    dinv     = (float*)w;            w += (size_t)N * sizeof(float);
    int*      nodeStart= (int*)w;              w += (size_t)N * sizeof(int);
    int*      nodeEnd  = (int*)w;              w += (size_t)N * sizeof(int);
    int*      binTotal = (int*)w;              w += (size_t)NBINS * sizeof(int);

    hipMemsetAsync(binTotal, 0, NBINS * sizeof(int), stream);

    int gGemm1 = (N + 31) / 32;                 // 313
    int gScat  = (E + EPB - 1) / EPB;           // 157
    fused_gemm_scatter<<<gGemm1 + gScat, 512, 0, stream>>>(
        X, W1, Y, src, dst, binTotal, binned, E, N, gGemm1);
    sort_bins<<<NBINS, 256, 0, stream>>>(binTotal, binned, csr16, dinv,
                                         nodeStart, nodeEnd, Y, Zb, N);

    int gAgg = (N + 3) / 4;
    aggregate<<<gAgg, 256, 0, stream>>>(Zb, nodeStart, nodeEnd, csr16, dinv, b1, out, N);

    int gGemm2 = (N + 15) / 16;
    gemm_scale<<<gGemm2, 256, 0, stream>>>(out, W2, dinv, Zb, N);
    aggregate<<<gAgg, 256, 0, stream>>>(Zb, nodeStart, nodeEnd, csr16, dinv, b2, out, N);
}

// Round 10
// 143.016 us; speedup vs baseline: 1.1120x; 1.0003x over previous
//
#include <hip/hip_runtime.h>
#include <hip/hip_bf16.h>

#define D 128
#define NBINS 157    // ceil(10000/64) bins of 64 nodes (dst >> 6)
#define BIN_CAP 5120 // mean 4076 + pad(<=448) + headroom
#define EPB 4096     // edges per scatter block (512 thr x 8)

__device__ __forceinline__ unsigned rne_bf16(float f) {
    unsigned u = __float_as_uint(f);
    return (u + 0x7FFFu + ((u >> 16) & 1u)) >> 16;
}
__device__ __forceinline__ float bf16_lo(unsigned u) { return __uint_as_float(u << 16); }
__device__ __forceinline__ float bf16_hi(unsigned u) { return __uint_as_float(u & 0xFFFF0000u); }

// ---------- K1: fused [Y = X@W (unscaled, fp32)] + [bin_scatter] ----------
__global__ __launch_bounds__(512) void fused_gemm_scatter(
        const float* __restrict__ X, const float* __restrict__ W,
        float* __restrict__ Y,
        const int* __restrict__ src, const int* __restrict__ dst,
        int* __restrict__ binTotal, int* __restrict__ binned,
        int E, int N, int gGemm) {
    __shared__ float smem[D * D];   // 64 KB, dual-purpose
    int tid = threadIdx.x;

    if ((int)blockIdx.x < gGemm) {
        {
            const float4* W4 = (const float4*)W;
            float4* Ws4 = (float4*)smem;
            #pragma unroll
            for (int i = 0; i < 8; ++i)
                Ws4[tid + 512 * i] = W4[tid + 512 * i];
        }
        __syncthreads();
        const float2* Ws2 = (const float2*)smem;
        int col2 = tid & 63;
        int wv   = __builtin_amdgcn_readfirstlane(tid >> 6);   // 0..7
        int row0 = blockIdx.x * 32 + wv * 4;
        if (row0 >= N) return;

        const float4* xr[4];
        #pragma unroll
        for (int r = 0; r < 4; ++r) {
            int rr = row0 + r; if (rr > N - 1) rr = N - 1;
            xr[r] = (const float4*)(X + (size_t)rr * D);
        }
        float accx[4] = {0.f, 0.f, 0.f, 0.f};
        float accy[4] = {0.f, 0.f, 0.f, 0.f};
        #pragma unroll 8
        for (int kb = 0; kb < 32; ++kb) {
            float4 xv[4];
            #pragma unroll
            for (int r = 0; r < 4; ++r) xv[r] = xr[r][kb];
            #pragma unroll
            for (int kk = 0; kk < 4; ++kk) {
                float2 w = Ws2[(4 * kb + kk) * 64 + col2];
                #pragma unroll
                for (int r = 0; r < 4; ++r) {
                    float xs = ((const float*)&xv[r])[kk];
                    accx[r] = fmaf(xs, w.x, accx[r]);
                    accy[r] = fmaf(xs, w.y, accy[r]);
                }
            }
        }
        #pragma unroll
        for (int r = 0; r < 4; ++r) {
            int rr = row0 + r;
            if (rr < N)
                ((float2*)Y)[(size_t)rr * 64 + col2] = make_float2(accx[r], accy[r]);
        }
    } else {
        int* cnt   = (int*)smem;
        int* loff  = cnt + 160;
        int* gbase = cnt + 320;
        int* scur  = cnt + 480;
        int* stage = cnt + 640;      // 4096 ints
        for (int b = tid; b < NBINS; b += 512) cnt[b] = 0;
        __syncthreads();

        int bid = blockIdx.x - gGemm;
        int base = bid * EPB + tid * 8;
        int s[8], dl[8], bn[8];
        int ne = 0;
        if (base + 8 <= E) {
            const int4* s4 = (const int4*)(src + base);
            const int4* d4 = (const int4*)(dst + base);
            int4 a0 = s4[0], a1 = s4[1], c0 = d4[0], c1 = d4[1];
            int ss[8] = {a0.x, a0.y, a0.z, a0.w, a1.x, a1.y, a1.z, a1.w};
            int dd[8] = {c0.x, c0.y, c0.z, c0.w, c1.x, c1.y, c1.z, c1.w};
            ne = 8;
            #pragma unroll
            for (int i = 0; i < 8; ++i) { s[i] = ss[i]; bn[i] = dd[i] >> 6; dl[i] = dd[i] & 63; }
        } else {
            for (int i = 0; i < 8; ++i) {
                int e = base + i;
                if (e < E) { s[ne] = src[e]; int d = dst[e]; bn[ne] = d >> 6; dl[ne] = d & 63; ++ne; }
            }
        }
        for (int i = 0; i < ne; ++i) atomicAdd(&cnt[bn[i]], 1);   // native ds_add (int)
        __syncthreads();

        if (tid < NBINS) gbase[tid] = atomicAdd(&binTotal[tid], cnt[tid]);
        if (tid < 64) {
            int c0 = (3 * tid     < NBINS) ? cnt[3 * tid    ] : 0;
            int c1 = (3 * tid + 1 < NBINS) ? cnt[3 * tid + 1] : 0;
            int c2 = (3 * tid + 2 < NBINS) ? cnt[3 * tid + 2] : 0;
            int tsum = c0 + c1 + c2;
            int incl = tsum;
            #pragma unroll
            for (int off = 1; off < 64; off <<= 1) {
                int t = __shfl_up(incl, off);
                if (tid >= off) incl += t;
            }
            int excl = incl - tsum;
            if (3 * tid     < NBINS) loff[3 * tid    ] = excl;
            if (3 * tid + 1 < NBINS) loff[3 * tid + 1] = excl + c0;
            if (3 * tid + 2 < NBINS) loff[3 * tid + 2] = excl + c0 + c1;
        }
        __syncthreads();
        if (tid < NBINS) scur[tid] = loff[tid];
        __syncthreads();

        for (int i = 0; i < ne; ++i) {
            int p = atomicAdd(&scur[bn[i]], 1);
            stage[p] = s[i] | (dl[i] << 14);      // src | dstLocal<<14
        }
        __syncthreads();

        int wv = tid >> 6, lane = tid & 63;
        for (int b = wv; b < NBINS; b += 8) {
            int n = cnt[b], so = loff[b], go = b * BIN_CAP + gbase[b];
            for (int i = lane; i < n; i += 64) binned[go + i] = stage[so + i];
        }
    }
}

// ---------- K2: counting sort (padded x8, sentinel N) + dinv + scale Y -> bf16 Zb ----------
__global__ __launch_bounds__(256) void sort_bins(const int* __restrict__ binTotal,
                                                 const int* __restrict__ binned,
                                                 unsigned short* __restrict__ csr16,
                                                 float* __restrict__ dinv,
                                                 int* __restrict__ nodeStart,
                                                 int* __restrict__ nodeEnd,
                                                 const float* __restrict__ Y,
                                                 unsigned* __restrict__ Zb, int N) {
    __shared__ int h[4][64];
    __shared__ int cur[4][64];
    __shared__ float sdinv[64];
    __shared__ int padTot;
    __shared__ int stage[BIN_CAP];
    int b = blockIdx.x, tid = threadIdx.x;
    int wv = tid >> 6, lane = tid & 63;
    int cntb = binTotal[b];
    h[wv][lane] = 0;
    __syncthreads();
    const int* bp = binned + b * BIN_CAP;
    for (int i = tid; i < cntb; i += 256) atomicAdd(&h[wv][bp[i] >> 14], 1);
    __syncthreads();
    if (tid < 64) {
        int d0 = h[0][tid], d1 = h[1][tid], d2 = h[2][tid], d3 = h[3][tid];
        int deg = d0 + d1 + d2 + d3;
        int pdeg = (deg + 7) & ~7;            // pad to multiple of 8
        int incl = pdeg;
        #pragma unroll
        for (int off = 1; off < 64; off <<= 1) {
            int t = __shfl_up(incl, off);
            if (tid >= off) incl += t;
        }
        int excl = incl - pdeg;
        cur[0][tid] = excl;
        cur[1][tid] = excl + d0;
        cur[2][tid] = excl + d0 + d1;
        cur[3][tid] = excl + d0 + d1 + d2;
        float dv = rsqrtf((float)(deg + 1));  // +1 self loop
        sdinv[tid] = dv;
        if (tid == 63) padTot = incl;
        int node = b * 64 + tid;
        if (node < N) {
            dinv[node]      = dv;
            nodeStart[node] = b * BIN_CAP + excl;
            nodeEnd[node]   = b * BIN_CAP + excl + pdeg;
        }
    }
    __syncthreads();
    int cntPad = padTot;
    for (int i = tid; i < cntPad; i += 256) stage[i] = N;   // sentinel = zero row
    __syncthreads();
    for (int i = tid; i < cntb; i += 256) {
        int p = bp[i];
        int pos = atomicAdd(&cur[wv][p >> 14], 1);
        stage[pos] = p & 0x3FFF;
    }
    // scale + convert: Zb[node] = bf16(Y[node] * dinv)  (rows owned exclusively)
    {
        const float4* Y4 = (const float4*)Y;
        uint2* Zb2 = (uint2*)Zb;            // 8 B = 4 bf16
        #pragma unroll
        for (int i = 0; i < 8; ++i) {
            int idx = tid + 256 * i;        // 64 rows x 32 quads
            int row = idx >> 5, c = idx & 31;
            int node = b * 64 + row;
            if (node < N) {
                float4 v = Y4[(size_t)node * 32 + c];
                float dv = sdinv[row];
                uint2 o;
                o.x = (rne_bf16(v.y * dv) << 16) | rne_bf16(v.x * dv);
                o.y = (rne_bf16(v.w * dv) << 16) | rne_bf16(v.z * dv);
                Zb2[(size_t)node * 32 + c] = o;
            }
        }
    }
    // zero sentinel row N (persists for layer 2: gemm writes only rows < N)
    if (b == 0 && tid < 64) Zb[(size_t)N * 64 + tid] = 0u;
    __syncthreads();
    unsigned short* bw = csr16 + b * BIN_CAP;
    for (int i = tid; i < cntPad; i += 256) bw[i] = (unsigned short)stage[i];
}

// ---------- GEMM (layer 2): Zb[row] = bf16((X[row] @ W) * dinv[row]) ----------
__global__ __launch_bounds__(256) void gemm_scale(const float* __restrict__ X,
                                                  const float* __restrict__ W,
                                                  const float* __restrict__ dinv,
                                                  unsigned* __restrict__ Zb, int N) {
    __shared__ float Ws[D * D];
    {
        const float4* W4 = (const float4*)W;
        float4* Ws4 = (float4*)Ws;
        #pragma unroll
        for (int i = 0; i < 16; ++i)
            Ws4[threadIdx.x + 256 * i] = W4[threadIdx.x + 256 * i];
    }
    __syncthreads();
    const float2* Ws2 = (const float2*)Ws;
    int col2 = threadIdx.x & 63;
    int wv   = __builtin_amdgcn_readfirstlane(threadIdx.x >> 6);
    int row0 = blockIdx.x * 16 + wv * 4;
    if (row0 >= N) return;

    const float4* xr[4];
    #pragma unroll
    for (int r = 0; r < 4; ++r) {
        int rr = row0 + r; if (rr > N - 1) rr = N - 1;
        xr[r] = (const float4*)(X + (size_t)rr * D);
    }
    float accx[4] = {0.f, 0.f, 0.f, 0.f};
    float accy[4] = {0.f, 0.f, 0.f, 0.f};
    #pragma unroll 8
    for (int kb = 0; kb < 32; ++kb) {
        float4 xv[4];
        #pragma unroll
        for (int r = 0; r < 4; ++r) xv[r] = xr[r][kb];
        #pragma unroll
        for (int kk = 0; kk < 4; ++kk) {
            float2 w = Ws2[(4 * kb + kk) * 64 + col2];
            #pragma unroll
            for (int r = 0; r < 4; ++r) {
                float xs = ((const float*)&xv[r])[kk];
                accx[r] = fmaf(xs, w.x, accx[r]);
                accy[r] = fmaf(xs, w.y, accy[r]);
            }
        }
    }
    #pragma unroll
    for (int r = 0; r < 4; ++r) {
        int rr = row0 + r;
        if (rr < N) {
            float dv = dinv[rr];
            Zb[(size_t)rr * 64 + col2] =
                (rne_bf16(accy[r] * dv) << 16) | rne_bf16(accx[r] * dv);
        }
    }
}

// ---------- aggregation: 2 nodes per wave, interleaved full-row uint4 gathers ----------
// 4 edge-groups x 16 lanes; per round each group gathers BOTH nodes' rows
// (2 independent 1KB wave-loads in flight per round). Degree imbalance within
// a pair is absorbed by sentinel row N (zero, L2-resident).
__global__ __launch_bounds__(256) void aggregate(const unsigned* __restrict__ Zb,
                                                 const int* __restrict__ nodeStart,
                                                 const int* __restrict__ nodeEnd,
                                                 const unsigned short* __restrict__ csr16,
                                                 const float* __restrict__ dinv,
                                                 const float* __restrict__ bias,
                                                 float* __restrict__ Out, int N) {
    int wv    = __builtin_amdgcn_readfirstlane(threadIdx.x >> 6);
    int nodeA = blockIdx.x * 8 + wv * 2;
    if (nodeA >= N) return;
    int nodeB = nodeA + 1;
    bool hasB = (nodeB < N);
    int lane = threadIdx.x & 63;
    int g    = lane >> 4;       // 0..3 edge sub-group
    int l16  = lane & 15;       // uint4 slot within 256 B row

    const uint4* Z4 = (const uint4*)Zb;     // row = 16 uint4
    float a0=0.f,a1=0.f,a2=0.f,a3=0.f,a4=0.f,a5=0.f,a6=0.f,a7=0.f;
    float b0=0.f,b1v=0.f,b2v=0.f,b3=0.f,b4v=0.f,b5=0.f,b6=0.f,b7=0.f;

    int eA = nodeStart[nodeA], endA = nodeEnd[nodeA];
    int eB = 0, endB = 0;
    if (hasB) { eB = nodeStart[nodeB]; endB = nodeEnd[nodeB]; }

    while (eA < endA || eB < endB) {
        int remA = endA - eA; int cntA = remA > 64 ? 64 : (remA > 0 ? remA : 0);
        int remB = endB - eB; int cntB = remB > 64 ? 64 : (remB > 0 ? remB : 0);
        int myA = (lane < cntA) ? (int)csr16[eA + lane] : N;   // sentinel pad
        int myB = (lane < cntB) ? (int)csr16[eB + lane] : N;
        int cmax = cntA > cntB ? cntA : cntB;
        int rounds = cmax >> 2;             // cnts are multiples of 8 (or 0)
        #pragma unroll 16
        for (int j = 0; j < rounds; ++j) {
            int idxA = __shfl(myA, j * 4 + g);
            int idxB = __shfl(myB, j * 4 + g);
            uint4 ua = Z4[idxA * 16 + l16];
            uint4 ub = Z4[idxB * 16 + l16];
            a0 += bf16_lo(ua.x); a1 += bf16_hi(ua.x);
            a2 += bf16_lo(ua.y); a3 += bf16_hi(ua.y);
            a4 += bf16_lo(ua.z); a5 += bf16_hi(ua.z);
            a6 += bf16_lo(ua.w); a7 += bf16_hi(ua.w);
            b0  += bf16_lo(ub.x); b1v += bf16_hi(ub.x);
            b2v += bf16_lo(ub.y); b3  += bf16_hi(ub.y);
            b4v += bf16_lo(ub.z); b5  += bf16_hi(ub.z);
            b6  += bf16_lo(ub.w); b7  += bf16_hi(ub.w);
        }
        eA += cntA; eB += cntB;
    }
    // reduce across the 4 edge-groups (lane bits 4..5)
    #pragma unroll
    for (int m = 16; m <= 32; m <<= 1) {
        a0 += __shfl_xor(a0, m); a1 += __shfl_xor(a1, m);
        a2 += __shfl_xor(a2, m); a3 += __shfl_xor(a3, m);
        a4 += __shfl_xor(a4, m); a5 += __shfl_xor(a5, m);
        a6 += __shfl_xor(a6, m); a7 += __shfl_xor(a7, m);
        b0  += __shfl_xor(b0, m);  b1v += __shfl_xor(b1v, m);
        b2v += __shfl_xor(b2v, m); b3  += __shfl_xor(b3, m);
        b4v += __shfl_xor(b4v, m); b5  += __shfl_xor(b5, m);
        b6  += __shfl_xor(b6, m);  b7  += __shfl_xor(b7, m);
    }
    // lanes 0-15 write node A; lanes 16-31 write node B
    int half = lane >> 4;
    if (half == 0 || (half == 1 && hasB)) {
        int node = half ? nodeB : nodeA;
        float r0 = half ? b0  : a0, r1 = half ? b1v : a1;
        float r2 = half ? b2v : a2, r3 = half ? b3  : a3;
        float r4 = half ? b4v : a4, r5 = half ? b5  : a5;
        float r6 = half ? b6  : a6, r7 = half ? b7  : a7;
        uint4 su = Z4[node * 16 + l16];
        float dv = dinv[node];
        const float4* bp4 = (const float4*)bias;
        float4 ba = bp4[l16 * 2], bb = bp4[l16 * 2 + 1];
        float4 o0, o1;
        o0.x = (r0 + bf16_lo(su.x)) * dv + ba.x;
        o0.y = (r1 + bf16_hi(su.x)) * dv + ba.y;
        o0.z = (r2 + bf16_lo(su.y)) * dv + ba.z;
        o0.w = (r3 + bf16_hi(su.y)) * dv + ba.w;
        o1.x = (r4 + bf16_lo(su.z)) * dv + bb.x;
        o1.y = (r5 + bf16_hi(su.z)) * dv + bb.y;
        o1.z = (r6 + bf16_lo(su.w)) * dv + bb.z;
        o1.w = (r7 + bf16_hi(su.w)) * dv + bb.w;
        float4* op = (float4*)Out + (size_t)node * 32 + l16 * 2;
        op[0] = o0;
        op[1] = o1;
    }
}

extern "C" void kernel_launch(void* const* d_in, const int* in_sizes, int n_in,
                              void* d_out, int out_size, void* d_ws, size_t ws_size,
                              hipStream_t stream) {
    const float* X  = (const float*)d_in[0];
    const int*   ed = (const int*)d_in[1];
    const float* W1 = (const float*)d_in[2];
    const float* b1 = (const float*)d_in[3];
    const float* W2 = (const float*)d_in[4];
    const float* b2 = (const float*)d_in[5];
    float* out = (float*)d_out;

    const int N = in_sizes[0] / D;       // 10000
    const int E = in_sizes[1] / 2;       // 640000
    const int* src = ed;
    const int* dst = ed + E;

    char* w = (char*)d_ws;
    float*    Y        = (float*)w;            w += (size_t)N * D * sizeof(float);
    unsigned* Zb       = (unsigned*)w;         w += (size_t)(N + 1) * 64 * sizeof(unsigned);
    int*      binned   = (int*)w;              w += (size_t)NBINS * BIN_CAP * sizeof(int);
    unsigned short* csr16 = (unsigned short*)w; w += (size_t)NBINS * BIN_CAP * sizeof(unsigned short);
    float*    dinv     = (float*)w;            w += (size_t)N * sizeof(float);
    int*      nodeStart= (int*)w;              w += (size_t)N * sizeof(int);
    int*      nodeEnd  = (int*)w;              w += (size_t)N * sizeof(int);
    int*      binTotal = (int*)w;              w += (size_t)NBINS * sizeof(int);

    hipMemsetAsync(binTotal, 0, NBINS * sizeof(int), stream);

    int gGemm1 = (N + 31) / 32;                 // 313
    int gScat  = (E + EPB - 1) / EPB;           // 157
    fused_gemm_scatter<<<gGemm1 + gScat, 512, 0, stream>>>(
        X, W1, Y, src, dst, binTotal, binned, E, N, gGemm1);
    sort_bins<<<NBINS, 256, 0, stream>>>(binTotal, binned, csr16, dinv,
                                         nodeStart, nodeEnd, Y, Zb, N);

    int gAgg = (N + 7) / 8;
    aggregate<<<gAgg, 256, 0, stream>>>(Zb, nodeStart, nodeEnd, csr16, dinv, b1, out, N);

    int gGemm2 = (N + 15) / 16;
    gemm_scale<<<gGemm2, 256, 0, stream>>>(out, W2, dinv, Zb, N);
    aggregate<<<gAgg, 256, 0, stream>>>(Zb, nodeStart, nodeEnd, csr16, dinv, b2, out, N);
}